// Round 9
// baseline (604.601 us; speedup 1.0000x reference)
//
#include <hip/hip_runtime.h>
#include <math.h>

// PixelQueryNet fused kernel, v9: write-early/barrier-late pipeline.
// Per low-res cell (b,i,j): MLP 4->64->64->64->64->3 (leaky 0.01, tanh) on the
// 64 pixels of its 8x8 tile; weights from lr_params[b,c,i,j] (channel stride
// PLANE=4096 floats).
//
// Block = 256 threads = 4 cells(j) x 8 pixel-rows(pg) x 8 co-blocks(cob);
// y[8co][8px] in registers. LDS = A (64KB) + W dbuf (8.3KB) -> 2 blocks/CU.
// Grid = 2048; siblings n,n+8,n+16,n+24 (same XCD) take the four 16B j-quads
// of each 64B weight line -> L2 sharing (FETCH ideal, proven R4-R8).
//
// v9 restructure (evidence: R4-R8 all pinned at VALUBusy ~37-41%; half of all
// VALU issue was non-FMA overhead; sched_barrier walls + write->drain->read
// turnaround serialized every phase):
//  * 48 phases of 4 ci (256ch), ONE raw s_barrier each, placed AFTER compute;
//    W(p+1) written at phase p start -> ds_write->read gap = full phase.
//  * No sched_barrier(0): compiler interleaves staging into the FMA stream.
//  * Specialized hot loop: static buf parity, pointer math in SALU, no
//    tile_desc. Bias loaded a layer ahead, added at flush (y starts at 0).
//  * L0/L4 via direct per-thread loads outside the pipeline.

static constexpr int PLANE = 4096;
static constexpr int NPAR  = 12995;
static constexpr int WROW  = 260;    // words per j-row in W tile (banks even)
static constexpr int AHI   = 8192;   // word offset of k4..7 activation plane

__device__ __forceinline__ float leaky(float v) { return fmaxf(v, 0.01f * v); }

// PE x-features, compile-time: cos/sin(2*pi*k/8), k = dx.
__device__ __forceinline__ constexpr float cx(int k) {
  constexpr float R = 0.70710678118654752f;
  const float t[8] = {1.f, R, 0.f, -R, -1.f, -R, 0.f, R};
  return t[k];
}
__device__ __forceinline__ constexpr float sx(int k) {
  constexpr float R = 0.70710678118654752f;
  const float t[8] = {0.f, R, 1.f, R, 0.f, -R, -1.f, -R};
  return t[k];
}

__global__ __launch_bounds__(256, 2) void pqn(const float* __restrict__ lr,
                                              float* __restrict__ out) {
  __shared__ alignas(16) float A[2 * AHI];        // 65536 B activations
  __shared__ alignas(16) float WB[2][4 * WROW];   // 8320 B weight tiles

  const int tid = threadIdx.x;
  const int j   = tid & 3;
  const int pg  = (tid >> 2) & 7;      // pixel row (dy)
  const int cob = tid >> 5;            // 0..7

  // ---- swizzle: 4 siblings (same XCD) cover one 64B weight line
  const int n  = blockIdx.x;
  const int e2 = (n >> 3) & 3;
  const int P  = (n & 7) | ((n >> 5) << 3);   // 0..511
  const int jg = ((P & 3) << 2) | e2;         // 0..15
  const int i  = (P >> 2) & 63;
  const int b  = (P >> 8) & 1;

  const float* __restrict__ sbase =
      lr + (size_t)b * NPAR * PLANE + (size_t)(i * 64 + jg * 4);
  const float* __restrict__ pt = sbase + j;   // per-thread channel base
  const int tplane = tid * PLANE;             // staging channel offset (words)

  float fyc, fys;
  sincosf(0.78539816339744830962f * pg, &fys, &fyc);

  const int abase = pg * 16 + j * 4;          // lane-contiguous A offset
  const int wrdq  = j * WROW + cob * 8;       // + cl*64 (+4 for q=1)

  float y[64];                                // [co 0..7][k 0..7]

  // stage-load for phase q (q uniform): 256 channels x this thread's j-quad
  auto ldst = [&](int q) -> float4 {
    const int c0 = 384 + (q >> 4) * 4160 + (q & 15) * 256;
    return *(const float4*)(sbase + (size_t)c0 * PLANE + tplane);
  };

  // ---- prologue: issue all independent loads
  float4 P0 = ldst(0), S1 = ldst(1), S2 = ldst(2), S3 = ldst(3), S0 = ldst(4);

  float bb[8];                                // bias of current hidden layer
#pragma unroll
  for (int m = 0; m < 8; ++m)
    bb[m] = pt[(size_t)(320 + cob * 8 + m) * PLANE];

  float l0b[8], l0w[32];
#pragma unroll
  for (int m = 0; m < 8; ++m) l0b[m] = pt[(size_t)(cob * 8 + m) * PLANE];
#pragma unroll
  for (int f = 0; f < 4; ++f)
#pragma unroll
    for (int m = 0; m < 8; ++m)
      l0w[f * 8 + m] = pt[(size_t)(64 + f * 64 + cob * 8 + m) * PLANE];

  // ---- L0 compute (y used as temp for activations)
#pragma unroll
  for (int co = 0; co < 8; ++co) {
#pragma unroll
    for (int k = 0; k < 8; ++k) {
      float v = l0b[co];
      v = fmaf(cx(k), l0w[co], v);
      v = fmaf(sx(k), l0w[8 + co], v);
      v = fmaf(fyc,   l0w[16 + co], v);
      v = fmaf(fys,   l0w[24 + co], v);
      y[co * 8 + k] = v;
    }
  }
  // stage WB[0] (phase 0) + publish L0 activations
#pragma unroll
  for (int jj = 0; jj < 4; ++jj)
    WB[0][jj * WROW + tid] = ((const float*)&P0)[jj];
#pragma unroll
  for (int co = 0; co < 8; ++co) {
    float4 v0, v1;
    v0.x = leaky(y[co * 8 + 0]); v0.y = leaky(y[co * 8 + 1]);
    v0.z = leaky(y[co * 8 + 2]); v0.w = leaky(y[co * 8 + 3]);
    v1.x = leaky(y[co * 8 + 4]); v1.y = leaky(y[co * 8 + 5]);
    v1.z = leaky(y[co * 8 + 6]); v1.w = leaky(y[co * 8 + 7]);
    *(float4*)&A[(cob * 8 + co) * 128 + abase]       = v0;
    *(float4*)&A[(cob * 8 + co) * 128 + abase + AHI] = v1;
  }
  asm volatile("s_waitcnt lgkmcnt(0)" ::: "memory");
  __builtin_amdgcn_s_barrier();

  // ---- one phase: U static (0..3), SW = staging reg for phase p+1
  auto phase = [&](int l, int t, int U, float4& SW) {
    const int p = l * 16 + t * 4 + U;
    if (p + 1 < 48) {                    // write W(p+1) -> other buffer
      float* wbuf = WB[(U + 1) & 1];
#pragma unroll
      for (int jj = 0; jj < 4; ++jj)
        wbuf[jj * WROW + tid] = ((const float*)&SW)[jj];
    }
    if (p + 5 < 48) SW = ldst(p + 5);    // refill staging reg (4-deep)
    const float* Wt = WB[U & 1];
    const int ab = (t * 4 + U) * 512;    // ci0 * 128
#pragma unroll
    for (int cl = 0; cl < 4; ++cl) {
      const float4 a0 = *(const float4*)&A[ab + cl * 128 + abase];
      const float4 a1 = *(const float4*)&A[ab + cl * 128 + abase + AHI];
      const float4 w0 = *(const float4*)&Wt[wrdq + cl * 64];
      const float4 w1 = *(const float4*)&Wt[wrdq + cl * 64 + 4];
      const float av[8] = {a0.x, a0.y, a0.z, a0.w, a1.x, a1.y, a1.z, a1.w};
      const float wv[8] = {w0.x, w0.y, w0.z, w0.w, w1.x, w1.y, w1.z, w1.w};
#pragma unroll
      for (int co = 0; co < 8; ++co)
#pragma unroll
        for (int k = 0; k < 8; ++k)
          y[co * 8 + k] = fmaf(av[k], wv[co], y[co * 8 + k]);
    }
    asm volatile("s_waitcnt lgkmcnt(0)" ::: "memory");
    __builtin_amdgcn_s_barrier();
  };

  // ---- hidden layers
  for (int l = 0; l < 3; ++l) {
#pragma unroll
    for (int m = 0; m < 64; ++m) y[m] = 0.f;
    for (int t = 0; t < 4; ++t) {
      phase(l, t, 0, S1);
      phase(l, t, 1, S2);
      phase(l, t, 2, S3);
      phase(l, t, 3, S0);
    }
    // ---- flush: add bias, leaky, publish; reload bias for next layer
    float vv[64];
#pragma unroll
    for (int co = 0; co < 8; ++co)
#pragma unroll
      for (int k = 0; k < 8; ++k)
        vv[co * 8 + k] = leaky(y[co * 8 + k] + bb[co]);
    if (l < 2) {
#pragma unroll
      for (int m = 0; m < 8; ++m)
        bb[m] = pt[(size_t)(320 + (l + 1) * 4160 + cob * 8 + m) * PLANE];
    }
#pragma unroll
    for (int co = 0; co < 8; ++co) {
      float4 v0, v1;
      v0.x = vv[co * 8 + 0]; v0.y = vv[co * 8 + 1];
      v0.z = vv[co * 8 + 2]; v0.w = vv[co * 8 + 3];
      v1.x = vv[co * 8 + 4]; v1.y = vv[co * 8 + 5];
      v1.z = vv[co * 8 + 6]; v1.w = vv[co * 8 + 7];
      *(float4*)&A[(cob * 8 + co) * 128 + abase]       = v0;
      *(float4*)&A[(cob * 8 + co) * 128 + abase + AHI] = v1;
    }
    asm volatile("s_waitcnt lgkmcnt(0)" ::: "memory");
    __builtin_amdgcn_s_barrier();
  }

  // ---- epilogue: L4 (64 -> 3) + tanh
  float po[24];
#pragma unroll
  for (int m = 0; m < 24; ++m) po[m] = 0.f;
#pragma unroll
  for (int cl = 0; cl < 8; ++cl) {
    const int ci = cob * 8 + cl;
    const float4 a0 = *(const float4*)&A[ci * 128 + abase];
    const float4 a1 = *(const float4*)&A[ci * 128 + abase + AHI];
#pragma unroll
    for (int o = 0; o < 3; ++o) {
      const float w = pt[(size_t)(12803 + ci * 3 + o) * PLANE];
      po[o * 8 + 0] = fmaf(a0.x, w, po[o * 8 + 0]);
      po[o * 8 + 1] = fmaf(a0.y, w, po[o * 8 + 1]);
      po[o * 8 + 2] = fmaf(a0.z, w, po[o * 8 + 2]);
      po[o * 8 + 3] = fmaf(a0.w, w, po[o * 8 + 3]);
      po[o * 8 + 4] = fmaf(a1.x, w, po[o * 8 + 4]);
      po[o * 8 + 5] = fmaf(a1.y, w, po[o * 8 + 5]);
      po[o * 8 + 6] = fmaf(a1.z, w, po[o * 8 + 6]);
      po[o * 8 + 7] = fmaf(a1.w, w, po[o * 8 + 7]);
    }
  }
  asm volatile("s_waitcnt lgkmcnt(0)" ::: "memory");
  __builtin_amdgcn_s_barrier();        // all A reads done -> reuse A
  float* R = A;
#pragma unroll
  for (int m = 0; m < 24; m += 4)
    *(float4*)&R[tid * 28 + m] = *(float4*)&po[m];
  asm volatile("s_waitcnt lgkmcnt(0)" ::: "memory");
  __builtin_amdgcn_s_barrier();

  if (cob == 0) {                      // tid < 32: one (j, pg) per thread
#pragma unroll
    for (int o = 0; o < 3; ++o) {
      const float bias = pt[(size_t)(12800 + o) * PLANE];
      float s[8];
#pragma unroll
      for (int k = 0; k < 8; ++k) s[k] = bias;
#pragma unroll
      for (int cb = 0; cb < 8; ++cb) {
#pragma unroll
        for (int k = 0; k < 8; ++k)
          s[k] += R[(cb * 32 + tid) * 28 + o * 8 + k];
      }
      float4 v0, v1;
      v0.x = tanhf(s[0]); v0.y = tanhf(s[1]); v0.z = tanhf(s[2]); v0.w = tanhf(s[3]);
      v1.x = tanhf(s[4]); v1.y = tanhf(s[5]); v1.z = tanhf(s[6]); v1.w = tanhf(s[7]);
      float* op = out + (size_t)b * 786432 + (size_t)o * 262144 +
                  (size_t)(i * 8 + pg) * 512 + (size_t)((jg * 4 + j) * 8);
      *(float4*)op = v0;
      *(float4*)(op + 4) = v1;
    }
  }
}

extern "C" void kernel_launch(void* const* d_in, const int* in_sizes, int n_in,
                              void* d_out, int out_size, void* d_ws, size_t ws_size,
                              hipStream_t stream) {
  (void)in_sizes; (void)n_in; (void)d_ws; (void)ws_size; (void)out_size;
  const float* lr = (const float*)d_in[1];  // d_in[0] = highres (unused by the math)
  float* out = (float*)d_out;
  hipLaunchKernelGGL(pqn, dim3(2048), dim3(256), 0, stream, lr, out);
}